// Round 1
// 315.507 us; speedup vs baseline: 1.5206x; 1.5206x over previous
//
#include <hip/hip_runtime.h>
#include <math.h>

#define QD 256
#define QN 1024
#define TT 8192

typedef __bf16 bf16x8 __attribute__((ext_vector_type(8)));
typedef float  f32x16 __attribute__((ext_vector_type(16)));
typedef unsigned short ushort_t;
typedef unsigned short us8 __attribute__((ext_vector_type(8)));

// LDS map (k_mega), total 59776 bytes -> 2 blocks/CU (4 waves/SIMD)
#define PL  0        // A planes [3][16kc][64cl][16B] = 49152 ; after GEMM1: t-h [0,16K), t32 [16K,48K)
#define WS_ 49152    // wsS[256] f32
#define P1_ 50176    // p1S[256] f32
#define MU_ 51200    // muS[16][32] f32
#define LM_ 53248    // lnMu[32] f32
#define TN_ 53376    // tn2P[32][8] f32
#define LX_ 54400    // lmax[32][8] f32
#define TH_ 55424    // thr[32] f32
#define CN_ 55552    // cnt[32] i32
#define CC_ 55680    // candC[32][64] u16 = 4096
#define SMEM_TOTAL 59776

// exact 3-way bf16 split (truncation; x = h+m+l up to ~2^-21|x|)
__device__ __forceinline__ void split3(float x, ushort_t& h, ushort_t& m, ushort_t& l) {
    unsigned int xu = __float_as_uint(x);
    h = (ushort_t)(xu >> 16);
    float hf = __uint_as_float(xu & 0xFFFF0000u);
    float r1 = x - hf;                       // exact
    unsigned int r1u = __float_as_uint(r1);
    m = (ushort_t)(r1u >> 16);
    float mf = __uint_as_float(r1u & 0xFFFF0000u);
    float r2 = r1 - mf;                      // exact
    l = (ushort_t)(__float_as_uint(r2) >> 16);
}
__device__ __forceinline__ f32x16 MF(bf16x8 a, bf16x8 b, f32x16 c) {
    return __builtin_amdgcn_mfma_f32_32x32x16_bf16(a, b, c, 0, 0, 0);
}

// ---------- k_pre: codebook normalize (h-plane + fp32) AND [M=convw^T@proj] planes, wsum, p1 ----
// bx<256: 4 codes/block (1/wave). bx>=256: col = bx-256 (0..255 -> M col; 256 -> wsum; 257 -> p1)
__global__ __launch_bounds__(256) void k_pre(const float* __restrict__ convw,
                                             const float* __restrict__ proj,
                                             const float* __restrict__ cb,
                                             ushort_t* __restrict__ cbph,
                                             float* __restrict__ cbn,
                                             ushort_t* __restrict__ w2p,
                                             float* __restrict__ wsum,
                                             float* __restrict__ p1) {
    int bx = blockIdx.x, t = threadIdx.x;
    if (bx < 256) {
        int c = bx*4 + (t>>6), lane = t&63;
        float4 v = ((const float4*)(cb + (size_t)c*QD))[lane];
        float ss = v.x*v.x + v.y*v.y + v.z*v.z + v.w*v.w;
        #pragma unroll
        for (int off = 32; off > 0; off >>= 1) ss += __shfl_down(ss, off);
        ss = __shfl(ss, 0);
        float inv = 1.0f/fmaxf(sqrtf(ss), 1e-12f);
        float4 vn = make_float4(v.x*inv, v.y*inv, v.z*inv, v.w*inv);
        *(float4*)(cbn + (size_t)c*QD + 4*lane) = vn;
        float vals[4] = {vn.x, vn.y, vn.z, vn.w};
        #pragma unroll
        for (int i = 0; i < 4; ++i) {
            int k = 4*lane + i;
            size_t base = ((size_t)(k>>4)*32 + (c>>5))*512 + (((k>>3)&1)*32 + (c&31))*8 + (k&7);
            cbph[base] = (ushort_t)(__float_as_uint(vals[i]) >> 16);
        }
    } else {
        int col = bx - 256;
        __shared__ float colv[512];
        if (col < 256) {
            const float* src = proj + col;
            colv[t]       = src[(size_t)t * 256];
            colv[t + 256] = src[(size_t)(t + 256) * 256];
            __syncthreads();
            float acc = 0.f;
            #pragma unroll 8
            for (int d = 0; d < 512; ++d) acc += convw[d*256 + t] * colv[d];
            ushort_t hb, mb, lb; split3(acc, hb, mb, lb);
            size_t base = ((size_t)(t>>4)*8 + (col>>5))*512 + (((t>>3)&1)*32 + (col&31))*8 + (t&7);
            w2p[base] = hb;
            w2p[base + 65536] = mb;
            w2p[base + 131072] = lb;
        } else if (col == 256) {
            float s = 0.f;
            #pragma unroll 8
            for (int d = 0; d < 512; ++d) s += convw[d*256 + t];
            wsum[t] = s;
        } else {
            float s = 0.f;
            #pragma unroll 8
            for (int d = 0; d < 512; ++d) s += proj[d*256 + t];
            p1[t] = s;
        }
    }
}

// ---------- k_mega: 32 tokens/block. patch->split3 -> GEMM1(M, 6 prod) -> t=V-mu*p1 ->
//            GEMM2 hh-screen (margin-safe) -> exact fp32 refine of ~3 candidates -> argmax ----
__global__ __launch_bounds__(512, 4) void k_mega(const float* __restrict__ fbank,
                                                 const ushort_t* __restrict__ w2p,
                                                 const ushort_t* __restrict__ cbph,
                                                 const float* __restrict__ cbn,
                                                 const float* __restrict__ wsum,
                                                 const float* __restrict__ p1,
                                                 int* __restrict__ out) {
    __shared__ char smem[SMEM_TOTAL];
    float* wsS   = (float*)(smem + WS_);
    float* p1S   = (float*)(smem + P1_);
    float* muS   = (float*)(smem + MU_);
    float* lnMuS = (float*)(smem + LM_);
    float* tn2P  = (float*)(smem + TN_);
    float* lmaxS = (float*)(smem + LX_);
    float* thrS  = (float*)(smem + TH_);
    int*   cntS  = (int*)(smem + CN_);
    ushort_t* candS = (ushort_t*)(smem + CC_);

    int tid = threadIdx.x;
    int n0 = blockIdx.x * 32;
    int w = tid >> 6, lane = tid & 63;
    int n31 = lane & 31, h = lane >> 5;
    size_t loff = (size_t)lane * 16;
    const char* w2pc = (const char*)w2p;
    const char* cbhc = (const char*)cbph;

    // ---- prefetch fbank (4 float4/thread, in flight across B1) ----
    float4 va[2], vb[2];
    #pragma unroll
    for (int i = 0; i < 2; ++i) {
        int id = tid + 512*i;
        int kc = id >> 6, cl = id & 63;
        int tok = cl & 31, hh2 = cl >> 5;
        int n = n0 + tok;
        int b = n >> 12, r = n & 4095, th = r >> 3, wm = r & 7;
        const float* src = fbank + ((size_t)(b*TT + th*16 + kc))*128 + wm*16 + hh2*8;
        va[i] = ((const float4*)src)[0];
        vb[i] = ((const float4*)src)[1];
    }
    if (tid < 256) wsS[tid] = wsum[tid];
    else           p1S[tid - 256] = p1[tid - 256];
    __syncthreads();                                   // B1: wsS/p1S ready

    // ---- stage patch -> 3 bf16 planes; mu partial (exact fp32 vals) folded in ----
    float mupart = 0.f;
    #pragma unroll
    for (int i = 0; i < 2; ++i) {
        int id = tid + 512*i;
        int kc = id >> 6, cl = id & 63;
        int hh2 = cl >> 5;
        float vals[8] = {va[i].x, va[i].y, va[i].z, va[i].w, vb[i].x, vb[i].y, vb[i].z, vb[i].w};
        us8 hv, mv, lv;
        #pragma unroll
        for (int j = 0; j < 8; ++j) {
            ushort_t a_, b_, c_; split3(vals[j], a_, b_, c_);
            hv[j] = a_; mv[j] = b_; lv[j] = c_;
            mupart += vals[j] * wsS[16*kc + 8*hh2 + j];
        }
        char* cp = smem + kc*1024 + cl*16;
        *(us8*)cp = hv;
        *(us8*)(cp + 16384) = mv;
        *(us8*)(cp + 32768) = lv;
    }
    muS[(tid>>5)*32 + (tid&31)] = mupart;
    __syncthreads();                                   // B2: planes + muS ready

    if (tid < 32) {
        float pm = 0.f;
        #pragma unroll
        for (int s = 0; s < 16; ++s) pm += muS[s*32 + tid];
        lnMuS[tid] = pm * (1.f/512.f);                 // published at B3
    }

    // ========== GEMM1: V[32][256] = patch @ M, split-3 (6 products), wave w -> cols 32w.. ======
    f32x16 accE, accO;
    #pragma unroll
    for (int r2 = 0; r2 < 16; ++r2) { accE[r2] = 0.f; accO[r2] = 0.f; }
    for (int kc = 0; kc < 16; kc += 2) {
        bf16x8 a0[3], a1[3], b0[3], b1[3];
        #pragma unroll
        for (int q = 0; q < 3; ++q) {
            b0[q] = *(const bf16x8*)(w2pc + (size_t)q*131072 + (size_t)(kc*8 + w)*1024 + loff);
            b1[q] = *(const bf16x8*)(w2pc + (size_t)q*131072 + (size_t)((kc+1)*8 + w)*1024 + loff);
            a0[q] = *(const bf16x8*)(smem + q*16384 + kc*1024 + loff);
            a1[q] = *(const bf16x8*)(smem + q*16384 + (kc+1)*1024 + loff);
        }
        accE = MF(a0[0], b0[0], accE); accO = MF(a1[0], b1[0], accO);
        accE = MF(a0[0], b0[1], accE); accO = MF(a1[0], b1[1], accO);
        accE = MF(a0[1], b0[0], accE); accO = MF(a1[1], b1[0], accO);
        accE = MF(a0[1], b0[1], accE); accO = MF(a1[1], b1[1], accO);
        accE = MF(a0[0], b0[2], accE); accO = MF(a1[0], b1[2], accO);
        accE = MF(a0[2], b0[0], accE); accO = MF(a1[2], b1[0], accO);
    }
    __syncthreads();                                   // B3: GEMM1 LDS reads done; lnMu ready

    // ---- t = V - mu*p1 (rs is argmax-neutral); write t32 (f32) + t-h (bf16 trunc); ||t||^2 ----
    {
        int q = 32*w + n31;
        float p1v = p1S[q];
        #pragma unroll
        for (int reg = 0; reg < 16; ++reg) {
            int tok = (reg&3) + 8*(reg>>2) + 4*h;
            float tv = (accE[reg] + accO[reg]) - lnMuS[tok]*p1v;
            *(float*)(smem + 16384 + tok*1024 + q*4) = tv;
            *(ushort_t*)(smem + (q>>4)*1024 + (((q>>3)&1)*32 + tok)*16 + (q&7)*2)
                = (ushort_t)(__float_as_uint(tv) >> 16);
            float sq2 = tv*tv;
            #pragma unroll
            for (int msk = 1; msk < 32; msk <<= 1) sq2 += __shfl_xor(sq2, msk);
            if (n31 == 0) tn2P[tok*8 + w] = sq2;
        }
    }
    __syncthreads();                                   // B4: t-h / t32 / tn2P ready

    // ========== GEMM2 screen: sim_hh = t_h @ cb_h^T, wave w -> tiles {w, w+8, w+16, w+24} ======
    f32x16 s0, s1, s2, s3;
    #pragma unroll
    for (int r2 = 0; r2 < 16; ++r2) { s0[r2]=0.f; s1[r2]=0.f; s2[r2]=0.f; s3[r2]=0.f; }
    for (int kc = 0; kc < 16; ++kc) {
        bf16x8 ah = *(const bf16x8*)(smem + kc*1024 + loff);
        bf16x8 q0 = *(const bf16x8*)(cbhc + (size_t)(kc*32 + w     )*1024 + loff);
        bf16x8 q1 = *(const bf16x8*)(cbhc + (size_t)(kc*32 + w + 8 )*1024 + loff);
        bf16x8 q2 = *(const bf16x8*)(cbhc + (size_t)(kc*32 + w + 16)*1024 + loff);
        bf16x8 q3 = *(const bf16x8*)(cbhc + (size_t)(kc*32 + w + 24)*1024 + loff);
        s0 = MF(ah, q0, s0); s1 = MF(ah, q1, s1);
        s2 = MF(ah, q2, s2); s3 = MF(ah, q3, s3);
    }
    // wave-local per-token max
    #pragma unroll
    for (int reg = 0; reg < 16; ++reg) {
        int tok = (reg&3) + 8*(reg>>2) + 4*h;
        float m = fmaxf(fmaxf(s0[reg], s1[reg]), fmaxf(s2[reg], s3[reg]));
        #pragma unroll
        for (int msk = 1; msk < 32; msk <<= 1) m = fmaxf(m, __shfl_xor(m, msk));
        if (n31 == 0) lmaxS[tok*8 + w] = m;
    }
    __syncthreads();                                   // B5
    if (tid < 32) {
        // |sim_true - sim_hh| <= (2^-6+2^-14)*||t|| + accum ~ 0.016*||t|| ; margin 0.02, window 0.04
        float g = -3.4e38f, sq = 0.f;
        #pragma unroll
        for (int p = 0; p < 8; ++p) { g = fmaxf(g, lmaxS[tid*8 + p]); sq += tn2P[tid*8 + p]; }
        thrS[tid] = g - 0.04f*sqrtf(sq);
        cntS[tid] = 0;
    }
    __syncthreads();                                   // B6
    // append candidates (true argmax provably >= thr)
    #pragma unroll
    for (int reg = 0; reg < 16; ++reg) {
        int tok = (reg&3) + 8*(reg>>2) + 4*h;
        float th_ = thrS[tok];
        if (s0[reg] >= th_) { int p = atomicAdd(&cntS[tok], 1); if (p < 64) candS[tok*64 + p] = (ushort_t)(32*(w     ) + n31); }
        if (s1[reg] >= th_) { int p = atomicAdd(&cntS[tok], 1); if (p < 64) candS[tok*64 + p] = (ushort_t)(32*(w + 8 ) + n31); }
        if (s2[reg] >= th_) { int p = atomicAdd(&cntS[tok], 1); if (p < 64) candS[tok*64 + p] = (ushort_t)(32*(w + 16) + n31); }
        if (s3[reg] >= th_) { int p = atomicAdd(&cntS[tok], 1); if (p < 64) candS[tok*64 + p] = (ushort_t)(32*(w + 24) + n31); }
    }
    __syncthreads();                                   // B7
    // ---- exact fp32 refine; wave w owns tokens 4w..4w+3; lowest-index tie-break ----
    #pragma unroll
    for (int tk = 0; tk < 4; ++tk) {
        int tok = 4*w + tk;
        float4 tv = *(const float4*)(smem + 16384 + tok*1024 + lane*16);
        int nc = min(cntS[tok], 64);
        float bv = -3.4e38f; int bi = 0x7fffffff;
        for (int c = 0; c < nc; ++c) {
            int code = candS[tok*64 + c];
            float4 cv = *(const float4*)(cbn + (size_t)code*256 + 4*lane);
            float d = tv.x*cv.x + tv.y*cv.y + tv.z*cv.z + tv.w*cv.w;
            #pragma unroll
            for (int msk = 1; msk < 64; msk <<= 1) d += __shfl_xor(d, msk);
            if (d > bv || (d == bv && code < bi)) { bv = d; bi = code; }
        }
        if (lane == 0) out[n0 + tok] = bi;
    }
}

extern "C" void kernel_launch(void* const* d_in, const int* in_sizes, int n_in,
                              void* d_out, int out_size, void* d_ws, size_t ws_size,
                              hipStream_t stream) {
    const float* fbank = (const float*)d_in[0];   // 16 x 8192 x 128
    const float* convw = (const float*)d_in[1];   // [512][256]
    const float* proj  = (const float*)d_in[2];   // [512][256]
    const float* cbook = (const float*)d_in[3];   // [1024][256]
    int* out = (int*)d_out;                       // 65536 int32

    char* ws = (char*)d_ws;
    ushort_t* cbph = (ushort_t*)ws;                  // 512 KB codebook h-plane
    float* cbn     = (float*)(ws + 0x080000);        // 1 MB normalized codebook fp32
    ushort_t* w2p  = (ushort_t*)(ws + 0x180000);     // 384 KB M planes (split-3)
    float* wsum    = (float*)(ws + 0x1E0000);        // 1 KB
    float* p1      = (float*)(ws + 0x1E1000);        // 1 KB

    hipLaunchKernelGGL(k_pre,  dim3(514),  dim3(256), 0, stream,
                       convw, proj, cbook, cbph, cbn, w2p, wsum, p1);
    hipLaunchKernelGGL(k_mega, dim3(2048), dim3(512), 0, stream,
                       fbank, w2p, cbph, cbn, wsum, p1, out);
}